// Round 6
// baseline (250.747 us; speedup 1.0000x reference)
//
#include <hip/hip_runtime.h>
#include <hip/hip_bf16.h>
#include <math.h>
#include <float.h>

// Problem constants (x: [8192,128] f32, n_images=2)
static constexpr int NN    = 8192;
static constexpr int DD    = 128;
static constexpr int PP    = 4096;              // persons
static constexpr int TILE  = 128;
static constexpr int TT    = NN / TILE;         // 64 tiles per dim
static constexpr int NBLK  = TT * (TT + 1) / 2; // 2080 upper-tri tile pairs
static constexpr int NPAIR = NBLK / 2;          // 1040 work items (2 tiles each)
static constexpr int NC    = NBLK * 2;          // 4160 candidates
static constexpr int GRP   = 1088;              // 8 rows x 128B (fp8) + 64B pad
static constexpr int PLDS  = 16 * GRP;          // 17408 B per 128x128 fp8 panel
static constexpr int NFB   = 768;               // persistent blocks = 3/CU

struct Cand { float v; unsigned idx; };

using f32x4 = __attribute__((ext_vector_type(4))) float;

typedef const __attribute__((address_space(1))) unsigned int* gas_uint;
typedef __attribute__((address_space(3))) unsigned int* las_uint;

// async 16B/lane global->LDS DMA. LDS dest = wave-uniform base + lane*16.
// Global address may vary per lane. [m03/m97/m104]
__device__ __forceinline__ void dma16(const void* g, const void* l) {
    __builtin_amdgcn_global_load_lds(
        (gas_uint)(unsigned long long)g,
        (las_uint)(unsigned)(unsigned long long)l, 16, 0, 0);
}

__device__ __forceinline__ void push1(float& v1, unsigned& i1, float& v2, unsigned& i2,
                                      float w, unsigned j) {
    if (w > v1) { v2 = v1; i2 = i1; v1 = w; i1 = j; }
    else if (w > v2) { v2 = w; i2 = j; }
}

__device__ __forceinline__ void merge2(float& v1, unsigned& i1, float& v2, unsigned& i2,
                                       float w1, unsigned j1, float w2, unsigned j2) {
    if (w1 > v1) {
        float nv2; unsigned ni2;
        if (v1 >= w2) { nv2 = v1; ni2 = i1; } else { nv2 = w2; ni2 = j2; }
        v1 = w1; i1 = j1; v2 = nv2; i2 = ni2;
    } else if (w1 > v2) {
        v2 = w1; i2 = j1;
    }
}

__device__ __forceinline__ void dmerge2(double& v1, unsigned& i1, double& v2,
                                        double w1, unsigned j1, double w2) {
    if (w1 > v1) {
        double nv2 = (v1 >= w2) ? v1 : w2;
        v2 = nv2; v1 = w1; i1 = j1;
    } else if (w1 > v2) {
        v2 = w1;
    }
}

// ---- kernel 0: x -> fp8 e4m3 copy (1MB) + sim_self (double) + ctrl reset ----
__global__ __launch_bounds__(256) void k_prep(const float* __restrict__ x,
                                              unsigned char* __restrict__ xb,
                                              double* __restrict__ ss,
                                              int* __restrict__ ctrl) {
    const int tid = threadIdx.x;
    if (blockIdx.x < 256) {
        if (blockIdx.x == 0 && tid == 0) { ctrl[0] = 0; ctrl[1] = 0; }
        int chunk = blockIdx.x * 256 + tid;      // 65536 chunks x 16 floats
        const float4* s = (const float4*)(x + (size_t)chunk * 16);
        float4 f0 = s[0], f1 = s[1], f2 = s[2], f3 = s[3];
        unsigned w0 = 0, w1 = 0, w2 = 0, w3 = 0;
        w0 = __builtin_amdgcn_cvt_pk_fp8_f32(f0.x, f0.y, w0, false);
        w0 = __builtin_amdgcn_cvt_pk_fp8_f32(f0.z, f0.w, w0, true);
        w1 = __builtin_amdgcn_cvt_pk_fp8_f32(f1.x, f1.y, w1, false);
        w1 = __builtin_amdgcn_cvt_pk_fp8_f32(f1.z, f1.w, w1, true);
        w2 = __builtin_amdgcn_cvt_pk_fp8_f32(f2.x, f2.y, w2, false);
        w2 = __builtin_amdgcn_cvt_pk_fp8_f32(f2.z, f2.w, w2, true);
        w3 = __builtin_amdgcn_cvt_pk_fp8_f32(f3.x, f3.y, w3, false);
        w3 = __builtin_amdgcn_cvt_pk_fp8_f32(f3.z, f3.w, w3, true);
        uint4 o = {w0, w1, w2, w3};
        *(uint4*)(xb + (size_t)chunk * 16) = o;
    } else {
        // 64 blocks: sim_self[p] = dot(x[p], x[p+1]) in double, wave per person
        int b = blockIdx.x - 256;          // 0..63
        const int wv = tid >> 6, lane = tid & 63;
        #pragma unroll 4
        for (int u = 0; u < 16; ++u) {
            int p = b * 64 + wv * 16 + u;  // 0..4095
            const float* a  = x + (size_t)p * DD;
            const float* bb = a + DD;
            double s = (double)a[lane] * (double)bb[lane]
                     + (double)a[lane + 64] * (double)bb[lane + 64];
            #pragma unroll
            for (int off = 32; off >= 1; off >>= 1) s += __shfl_down(s, off);
            if (lane == 0) ss[p] = s;
        }
    }
}

// stage one 128x128 fp8 panel: 4 dma16 per wave (16 groups of 8 rows x 128B).
// Source col XOR-swizzled by (row_in_group<<4) -> conflict-free fragment reads.
__device__ __forceinline__ void stage_panel(const unsigned char* xb, int trow,
                                            char* lds, int wv, int grow, int colb) {
    #pragma unroll
    for (int t = 0; t < 4; ++t) {
        int g = wv * 4 + t;
        dma16(xb + (size_t)(trow * TILE + g * 8 + grow) * DD + colb, lds + g * GRP);
    }
}

// one 128x128 tile: fp8 MFMA + top-2 epilogue. Uses raw barrier (NO vmcnt
// drain) so the caller's in-flight prefetch DMAs survive.
__device__ __forceinline__ void compute_tile(const char* As, const char* Bs,
                                             int ti, int tj, int wv, int lane, int tid,
                                             float* sv1, float* sv2,
                                             unsigned* si1, unsigned* si2,
                                             Cand* cands, int tau) {
    const int wm   = wv >> 1;
    const int wn   = wv & 1;
    const int quad = lane >> 4;
    const int r16  = lane & 15;
    const int rl   = r16 & 7;
    const int rh   = r16 >> 3;
    const int xs   = rl << 4;

    const char* Abase = As + (wm * 8 + rh) * GRP + rl * 128 + (quad & 1) * 8;
    const char* Bbase = Bs + (wn * 8 + rh) * GRP + rl * 128 + (quad & 1) * 8;

    f32x4 acc[4][4];
    #pragma unroll
    for (int mi = 0; mi < 4; ++mi)
        #pragma unroll
        for (int nj = 0; nj < 4; ++nj)
            acc[mi][nj] = (f32x4){0.f, 0.f, 0.f, 0.f};

    #pragma unroll
    for (int kc = 0; kc < 4; ++kc) {
        const int co = (kc * 32 + (quad >> 1) * 16) ^ xs;
        long af[4], bq[4];
        #pragma unroll
        for (int mi = 0; mi < 4; ++mi) {
            af[mi] = *(const long*)(Abase + mi * (2 * GRP) + co);
            bq[mi] = *(const long*)(Bbase + mi * (2 * GRP) + co);
        }
        #pragma unroll
        for (int mi = 0; mi < 4; ++mi)
            #pragma unroll
            for (int nj = 0; nj < 4; ++nj)
                acc[mi][nj] = __builtin_amdgcn_mfma_f32_16x16x32_fp8_fp8(
                    af[mi], bq[nj], acc[mi][nj], 0, 0, 0);
    }

    // C/D layout: col = lane&15, row = (lane>>4)*4 + reg (dtype-independent)
    const int ibase = ti * TILE + wm * 64;
    const int jbase = tj * TILE + wn * 64;
    float v1 = -INFINITY, v2 = -INFINITY;
    unsigned i1 = 0, i2 = 0;
    #pragma unroll
    for (int mi = 0; mi < 4; ++mi) {
        #pragma unroll
        for (int nj = 0; nj < 4; ++nj) {
            int gj = jbase + nj * 16 + r16;
            #pragma unroll
            for (int reg = 0; reg < 4; ++reg) {
                int gi = ibase + mi * 16 + quad * 4 + reg;
                if (gi < gj) {
                    unsigned idx = (unsigned)(gi * NN + gj);
                    push1(v1, i1, v2, i2, acc[mi][nj][reg], idx);
                }
            }
        }
    }
    #pragma unroll
    for (int off = 32; off >= 1; off >>= 1) {
        float    w1 = __shfl_down(v1, off);
        unsigned j1 = (unsigned)__shfl_down((int)i1, off);
        float    w2 = __shfl_down(v2, off);
        unsigned j2 = (unsigned)__shfl_down((int)i2, off);
        merge2(v1, i1, v2, i2, w1, j1, w2, j2);
    }
    if (lane == 0) { sv1[wv] = v1; si1[wv] = i1; sv2[wv] = v2; si2[wv] = i2; }
    asm volatile("s_waitcnt lgkmcnt(0)" ::: "memory");
    __builtin_amdgcn_s_barrier();
    if (tid == 0) {
        for (int w = 1; w < 4; ++w)
            merge2(v1, i1, v2, i2, sv1[w], si1[w], sv2[w], si2[w]);
        cands[tau * 2]     = {v1, i1};
        cands[tau * 2 + 1] = {v2, i2};
    }
}

// ---- kernel 1 (fused): persistent blocks, atomic-ticket pairs of tiles,
// A-panel shared within a pair, B1 prefetched under counted vmcnt(4).
// Last block to finish runs the finalize (approx top-2 -> exact f64 recheck
// -> closed-form mean). ----
__global__ __launch_bounds__(256, 3) void k_fused(const unsigned char* __restrict__ xb,
                                                  const float* __restrict__ x,
                                                  const double* __restrict__ ss,
                                                  Cand* __restrict__ cands,
                                                  int* __restrict__ ctrl,
                                                  float* __restrict__ out) {
    __shared__ __align__(16) char As[PLDS];
    __shared__ __align__(16) char Bs0[PLDS];
    __shared__ __align__(16) char Bs1[PLDS];
    __shared__ float sv1[4], sv2[4];
    __shared__ unsigned si1[4], si2[4];
    __shared__ int s_pair;
    __shared__ int s_last;

    const int tid  = threadIdx.x;
    const int wv   = tid >> 6;
    const int lane = tid & 63;
    const int grow = lane >> 3;                       // DMA row in group 0..7
    const int colb = ((lane & 7) * 16) ^ (grow << 4); // swizzled 16B chunk

    for (;;) {
        if (tid == 0) s_pair = atomicAdd(&ctrl[0], 1);
        asm volatile("s_waitcnt lgkmcnt(0)" ::: "memory");
        __builtin_amdgcn_s_barrier();                 // ALSO: post-pair cleanup
        const int pair = s_pair;
        if (pair >= NPAIR) break;

        const int tau0 = pair * 2;
        int rem = tau0, ti = 0;
        while (rem >= TT - ti) { rem -= (TT - ti); ++ti; }
        const int tj    = ti + rem;
        const bool sameA = (tj + 1 < TT);             // block-uniform
        const int ti1 = sameA ? ti : ti + 1;
        const int tj1 = sameA ? tj + 1 : ti + 1;

        if (sameA) {
            stage_panel(xb, ti,  As,  wv, grow, colb);
            stage_panel(xb, tj,  Bs0, wv, grow, colb);
            stage_panel(xb, tj1, Bs1, wv, grow, colb);    // prefetch tile1's B
            asm volatile("s_waitcnt vmcnt(4)" ::: "memory"); // A+B0 landed, B1 in flight
        } else {
            stage_panel(xb, ti,  As,  wv, grow, colb);
            stage_panel(xb, tj,  Bs0, wv, grow, colb);
            asm volatile("s_waitcnt vmcnt(0)" ::: "memory");
        }
        __builtin_amdgcn_sched_barrier(0);
        __builtin_amdgcn_s_barrier();

        compute_tile(As, Bs0, ti, tj, wv, lane, tid, sv1, sv2, si1, si2, cands, tau0);

        if (!sameA) {   // re-stage A for the row-crossing tile (6% of pairs);
                        // safe: compute_tile ended with lgkmcnt(0)+barrier
            stage_panel(xb, ti1, As,  wv, grow, colb);
            stage_panel(xb, tj1, Bs1, wv, grow, colb);
        }
        asm volatile("s_waitcnt vmcnt(0)" ::: "memory");  // B1 (+A) landed
        __builtin_amdgcn_sched_barrier(0);
        __builtin_amdgcn_s_barrier();

        compute_tile(As, Bs1, ti1, tj1, wv, lane, tid, sv1, sv2, si1, si2, cands, tau0 + 1);
    }

    // ---- last-block-done: fused finalize ----
    if (tid == 0) {
        __threadfence();                       // release our cands writes
        int c = atomicAdd(&ctrl[1], 1);
        s_last = (c == NFB - 1) ? 1 : 0;
    }
    __syncthreads();
    if (!s_last) return;
    __threadfence();                           // acquire all blocks' cands

    struct Fin {
        float redv[8]; float s_thresh; int cnt;
        unsigned qidx[256]; double qex[256];
        double wdv1[4], wdv2[4]; unsigned wdi[4];
        double sd1, sd2; unsigned stopi;
        double sacc[256];
    };
    Fin* F = (Fin*)As;                          // reuse dead LDS (5.5KB < 17.4KB)
    if (tid == 0) F->cnt = 0;

    // Phase A: approx global top-2 values
    float v1 = -INFINITY, v2 = -INFINITY;
    for (int e = tid; e < NC; e += 256) {
        float v = cands[e].v;
        if (v > v1) { v2 = v1; v1 = v; }
        else if (v > v2) v2 = v;
    }
    #pragma unroll
    for (int off = 32; off >= 1; off >>= 1) {
        float w1 = __shfl_down(v1, off);
        float w2 = __shfl_down(v2, off);
        if (w1 > v1) { v2 = (v1 >= w2) ? v1 : w2; v1 = w1; }
        else if (w1 > v2) v2 = w1;
    }
    if (lane == 0) { F->redv[wv * 2] = v1; F->redv[wv * 2 + 1] = v2; }
    __syncthreads();
    if (tid == 0) {
        float a1 = -INFINITY, a2 = -INFINITY;
        for (int e = 0; e < 8; ++e) {
            float v = F->redv[e];
            if (v > a1) { a2 = a1; a1 = v; }
            else if (v > a2) a2 = v;
        }
        F->s_thresh = a2 - 10.0f;   // margin >> fp8 dot-product error bound
    }
    __syncthreads();
    const float thresh = F->s_thresh;

    // Phase B: gather candidates within margin
    for (int e = tid; e < NC; e += 256) {
        if (cands[e].v >= thresh) {
            int k = atomicAdd(&F->cnt, 1);
            if (k < 256) F->qidx[k] = cands[e].idx;
        }
    }
    __syncthreads();
    const int n = F->cnt < 256 ? F->cnt : 256;

    // Phase C: exact double dot per candidate (one wave each)
    for (int c = wv; c < n; c += 4) {
        unsigned idx = F->qidx[c];
        unsigned gi = idx >> 13;
        unsigned gj = idx & 8191;
        const float* pa = x + (size_t)gi * DD;
        const float* pb = x + (size_t)gj * DD;
        double s = (double)pa[lane] * (double)pb[lane]
                 + (double)pa[lane + 64] * (double)pb[lane + 64];
        #pragma unroll
        for (int off = 32; off >= 1; off >>= 1) s += __shfl_down(s, off);
        if (lane == 0) F->qex[c] = s;
    }
    __syncthreads();

    // Phase D: exact top-2, parallel
    double d1 = -DBL_MAX, d2 = -DBL_MAX;
    unsigned bi = 0;
    if (tid < n) { d1 = F->qex[tid]; bi = F->qidx[tid]; }
    #pragma unroll
    for (int off = 32; off >= 1; off >>= 1) {
        double w1   = __shfl_down(d1, off);
        unsigned j1 = (unsigned)__shfl_down((int)bi, off);
        double w2   = __shfl_down(d2, off);
        dmerge2(d1, bi, d2, w1, j1, w2);
    }
    if (lane == 0) { F->wdv1[wv] = d1; F->wdv2[wv] = d2; F->wdi[wv] = bi; }
    __syncthreads();
    if (tid == 0) {
        for (int w = 1; w < 4; ++w)
            dmerge2(d1, bi, d2, F->wdv1[w], F->wdi[w], F->wdv2[w]);
        F->sd1 = d1; F->sd2 = d2; F->stopi = bi;
    }
    __syncthreads();
    const double top1 = F->sd1, top2 = F->sd2;
    const unsigned topi = F->stopi;

    // Phase E: mean(sim_oth / sim_self)
    double acc = 0.0;
    for (int p = tid; p < PP; p += 256) {
        unsigned selfidx = (unsigned)(p * NN + p + 1);
        double so = (topi == selfidx) ? top2 : top1;
        acc += so / ss[p];
    }
    F->sacc[tid] = acc;
    __syncthreads();
    for (int s = 128; s >= 1; s >>= 1) {
        if (tid < s) F->sacc[tid] += F->sacc[tid + s];
        __syncthreads();
    }
    if (tid == 0) out[0] = (float)(F->sacc[0] / (double)PP);
}

extern "C" void kernel_launch(void* const* d_in, const int* in_sizes, int n_in,
                              void* d_out, int out_size, void* d_ws, size_t ws_size,
                              hipStream_t stream) {
    (void)in_sizes; (void)n_in; (void)out_size; (void)ws_size;
    const float* x = (const float*)d_in[0];
    float* out = (float*)d_out;

    double* ss   = (double*)d_ws;                                 // 32 KB
    Cand* cands  = (Cand*)((char*)d_ws + 32768);                  // 33 KB
    int* ctrl    = (int*)((char*)d_ws + 81920);                   // ticket, done
    unsigned char* xb = (unsigned char*)((char*)d_ws + 131072);   // 1 MB fp8

    k_prep<<<320, 256, 0, stream>>>(x, xb, ss, ctrl);
    k_fused<<<NFB, 256, 0, stream>>>(xb, x, ss, cands, ctrl, out);
}